// Round 1
// baseline (841.378 us; speedup 1.0000x reference)
//
#include <hip/hip_runtime.h>

// SpeechClassificationLayer: 32768 items x (42 frames x 133 channels) f32.
// Only channels {0,2,3,5,36,132} matter. One wave per item; lane = frame.
// Window-of-5 sums via shfl_down tree; top-2 via two butterfly max-reductions.

#define NFRAMES 42
#define NCH     133
#define NWIN    38        // 42 - 5 + 1
#define NEGF    (-1e30f)

__global__ __launch_bounds__(256) void speech_kernel(const float* __restrict__ in,
                                                     float* __restrict__ out,
                                                     int n_items) {
    const int lane = threadIdx.x & 63;
    const int wave = threadIdx.x >> 6;
    const int b = blockIdx.x * 4 + wave;
    if (b >= n_items) return;

    // clamp lane->frame so lanes 42..63 do harmless (already-fetched-line) loads
    const int t = (lane < NFRAMES) ? lane : (NFRAMES - 1);
    const float* f = in + (size_t)b * (NFRAMES * NCH) + (size_t)t * NCH;

    const float v0   = f[0];
    const float v2   = f[2];
    const float v3   = f[3];
    const float v5   = f[5];
    const float v36  = f[36];
    const float v132 = f[132];

    // combos (priority order 0..5); comb0's second condition (v0 in [0,1]) is
    // kept for exactness with the reference.
    const bool in57 = (v0 >= 0.5f) & (v0 <= 0.7f);
    const bool ok0  = (v0 >= 0.6f) & (v0 <= 1.0f) & (v0 >= 0.0f);
    const bool ok1  = in57 & (v2   >= 0.3f) & (v2   <= 0.7f);
    const bool ok2  = in57 & (v3   >= 0.2f) & (v3   <= 0.5f);
    const bool ok3  = in57 & (v5   >= 0.2f) & (v5   <= 0.4f);
    const bool ok4  = in57 & (v132 >= 0.2f) & (v132 <= 0.5f);
    const bool ok5  = in57 & (v36  >= 0.1f) & (v36  <= 0.3f);

    const bool valid = (lane < NFRAMES);
    const bool fj = (ok0 | ok1 | ok2 | ok3 | ok4 | ok5) && valid;
    float fs = 0.0f;
    if (fj) {
        fs = ok0 ? 5.0f : ok1 ? 1.0f : ok2 ? 1.0f : ok3 ? 1.5f : ok4 ? 1.0f : 1.2f;
    }
    const int fc = fj ? 1 : 0;

    // sliding window of 5: ws[t] = sum fs[t..t+4], wc[t] = sum fc[t..t+4]
    float s2 = fs + __shfl_down(fs, 1);
    float s4 = s2 + __shfl_down(s2, 2);
    const float ws = s4 + __shfl_down(fs, 4);
    int c2i = fc + __shfl_down(fc, 1);
    int c4  = c2i + __shfl_down(c2i, 2);
    const int wc = c4 + __shfl_down(fc, 4);

    const bool gj = (wc >= 3) && (lane < NWIN);
    const float masked = gj ? ws : NEGF;

    const unsigned long long bal = __ballot(gj);
    const int true_count = __popcll(bal);

    // top-1 via butterfly max
    float m1 = masked;
    #pragma unroll
    for (int k = 32; k >= 1; k >>= 1) m1 = fmaxf(m1, __shfl_xor(m1, k));
    // exclude one instance of the max, then top-2
    const unsigned long long eq = __ballot(masked == m1);
    const int firstlane = __ffsll((unsigned long long)eq) - 1;
    float m2 = (lane == firstlane) ? NEGF : masked;
    #pragma unroll
    for (int k = 32; k >= 1; k >>= 1) m2 = fmaxf(m2, __shfl_xor(m2, k));

    if (lane == 0) {
        const bool final_j = (true_count >= 2);
        out[b] = final_j ? 1.0f : 0.0f;
        out[n_items + b] = final_j ? (m1 + m2) : 0.0f;
    }
}

extern "C" void kernel_launch(void* const* d_in, const int* in_sizes, int n_in,
                              void* d_out, int out_size, void* d_ws, size_t ws_size,
                              hipStream_t stream) {
    const float* in = (const float*)d_in[0];
    float* out = (float*)d_out;
    const int n_items = in_sizes[0] / (NFRAMES * NCH);
    const int blocks = (n_items + 3) / 4;   // 4 waves (items) per 256-thread block
    speech_kernel<<<blocks, 256, 0, stream>>>(in, out, n_items);
}